// Round 12
// baseline (787.621 us; speedup 1.0000x reference)
//
#include <hip/hip_runtime.h>
#include <hip/hip_bf16.h>

#define NT 8192      // tokens
#define DM 1024      // d_model
#define NE 8         // experts
#define DH 4096      // d_hidden
#define NP (NT * 2)  // token-expert pairs (TOP_K = 2)

typedef __attribute__((ext_vector_type(8))) __bf16 bf16x8;
typedef __attribute__((ext_vector_type(4))) float f32x4;

__device__ __forceinline__ ushort f2bf(float f) {
  unsigned int x = __float_as_uint(f);
  unsigned int r = (x + 0x7fffu + ((x >> 16) & 1u)) >> 16;  // RNE
  return (ushort)r;
}

// exact tanh-gelu, rearranged: 0.5x(1+tanh(z)) = x*e^{2z}/(e^{2z}+1)
__device__ __forceinline__ float gelu_fast(float x) {
  float x2 = x * x;
  float t = __builtin_fmaf(x2, 0.044715f, 1.0f);
  float m = x * t * 2.3025851f;
  m = fminf(m, 126.0f);
  float p = __builtin_amdgcn_exp2f(m);
  return x * p * __builtin_amdgcn_rcpf(p + 1.0f);
}

__device__ __forceinline__ void async_copy16(const void* gsrc, void* ldst) {
  __builtin_amdgcn_global_load_lds(
      (const __attribute__((address_space(1))) void*)gsrc,
      (__attribute__((address_space(3))) void*)ldst, 16, 0, 0);
}

// ---------------- fused pre-pass: ONE kernel, four independent block ranges ----------------
//   b < 4096 : weight transpose+cvt (w1 -> w1t, w2 -> w2t), 128x128 tiles
//   b < 4224 : gating, BLOCK-AGGREGATED (128 blocks x 64 tokens)
//   b < 6272 : inp -> bf16 streaming cast (2048 blocks)
//   b < 8320 : zero y (gemm2 accumulates into y with atomics)
// (r10-verified structure. r11's attempt to move w2T/y-zero into gemm1's grid
// failed correctness with a ~0.1 absmax — reverted; overlap upside was ~30us.)
__global__ __launch_bounds__(256) void fused_pre_kernel(
    const float* __restrict__ w1, const float* __restrict__ w2,
    ushort* __restrict__ w1t, ushort* __restrict__ w2t,
    const float* __restrict__ inp, const float* __restrict__ gw,
    const float* __restrict__ gb, ushort* __restrict__ inp_bf,
    int* __restrict__ counts, int* __restrict__ tok_list,
    float* __restrict__ scale_list, float* __restrict__ y) {
  __shared__ ushort tileT[128][136];   // transpose branch
  __shared__ int   lcnt[NE];           // gate branch
  __shared__ int   gbase[NE];
  __shared__ int   ltok[NE][64];       // per-token top2 experts are distinct -> <=64/expert
  __shared__ float lsc[NE][64];
  const int b = blockIdx.x;

  if (b < 4096) {
    // ---- transpose part: 128x128 tile, register 4x4 micro-transpose ----
    const int which = b >> 11;         // 0 = w1, 1 = w2
    const int rem = b & 2047;
    const int e = rem >> 8;            // expert
    const int bb = rem & 255;          // 256 tiles per expert-weight
    const float* src;
    ushort* dst;
    int R, C, r0, c0;
    if (which == 0) {
      src = w1 + (size_t)e * DM * DH; dst = w1t + (size_t)e * DM * DH;
      R = DM; C = DH;
      r0 = (bb & 7) * 128;   c0 = (bb >> 3) * 128;
    } else {
      src = w2 + (size_t)e * DM * DH; dst = w2t + (size_t)e * DM * DH;
      R = DH; C = DM;
      r0 = (bb & 31) * 128;  c0 = (bb >> 5) * 128;
    }
    const int tx = threadIdx.x & 31;
    const int ty = threadIdx.x >> 5;
#pragma unroll
    for (int i = 0; i < 4; i++) {
      int rb = ty + 8 * i;
      const float* sp = src + (size_t)(r0 + 4 * rb) * C + c0 + 4 * tx;
      float4 a0 = *(const float4*)(sp);
      float4 a1 = *(const float4*)(sp + C);
      float4 a2 = *(const float4*)(sp + 2 * (size_t)C);
      float4 a3 = *(const float4*)(sp + 3 * (size_t)C);
      ushort4 o0 = { f2bf(a0.x), f2bf(a1.x), f2bf(a2.x), f2bf(a3.x) };
      ushort4 o1 = { f2bf(a0.y), f2bf(a1.y), f2bf(a2.y), f2bf(a3.y) };
      ushort4 o2 = { f2bf(a0.z), f2bf(a1.z), f2bf(a2.z), f2bf(a3.z) };
      ushort4 o3 = { f2bf(a0.w), f2bf(a1.w), f2bf(a2.w), f2bf(a3.w) };
      *(ushort4*)(&tileT[4 * tx + 0][4 * rb]) = o0;
      *(ushort4*)(&tileT[4 * tx + 1][4 * rb]) = o1;
      *(ushort4*)(&tileT[4 * tx + 2][4 * rb]) = o2;
      *(ushort4*)(&tileT[4 * tx + 3][4 * rb]) = o3;
    }
    __syncthreads();
    const int kx = threadIdx.x & 31;
    const int ny = threadIdx.x >> 5;
#pragma unroll
    for (int i = 0; i < 16; i++) {
      int n = ny + 8 * i;
      *(ushort4*)(dst + (size_t)(c0 + n) * R + r0 + 4 * kx) =
          *(const ushort4*)(&tileT[n][4 * kx]);
    }
  } else if (b < 4224) {
    // ---- gating part: 64 tokens/block, block-aggregated appends ----
    const int t = threadIdx.x;
    if (t < NE) lcnt[t] = 0;
    __syncthreads();
    const int wave = t >> 6, lane = t & 63;
    const int tokBase = (b - 4096) * 64 + wave * 16;
    for (int ti = 0; ti < 16; ti++) {
      const int token = tokBase + ti;
      const float* x = inp + (size_t)token * DM;
      float acc[NE];
#pragma unroll
      for (int e = 0; e < NE; e++) acc[e] = 0.f;
#pragma unroll
      for (int j = 0; j < 16; j++) {
        int idx = j * 64 + lane;
        float xv = x[idx];
        const float4* g = (const float4*)(gw + (size_t)idx * NE);
        float4 g0 = g[0], g1 = g[1];
        acc[0] += xv * g0.x; acc[1] += xv * g0.y; acc[2] += xv * g0.z; acc[3] += xv * g0.w;
        acc[4] += xv * g1.x; acc[5] += xv * g1.y; acc[6] += xv * g1.z; acc[7] += xv * g1.w;
      }
#pragma unroll
      for (int e = 0; e < NE; e++) {
        for (int off = 32; off; off >>= 1) acc[e] += __shfl_xor(acc[e], off, 64);
      }
      if (lane == 0) {
        float v[NE];
#pragma unroll
        for (int e = 0; e < NE; e++) v[e] = acc[e] + gb[e];
        int i0 = 0; float b0 = v[0];
#pragma unroll
        for (int e = 1; e < NE; e++) if (v[e] > b0) { b0 = v[e]; i0 = e; }
        int i1 = -1; float b1v = -INFINITY;
#pragma unroll
        for (int e = 0; e < NE; e++) if (e != i0 && v[e] > b1v) { b1v = v[e]; i1 = e; }
        float s1 = 1.f / (1.f + __expf(b0 - b1v));  // softmax over the two selected logits
        float s0 = 1.f - s1;
        int p0 = atomicAdd(&lcnt[i0], 1);           // LDS atomic (fast)
        ltok[i0][p0] = token; lsc[i0][p0] = s0;
        int p1 = atomicAdd(&lcnt[i1], 1);
        ltok[i1][p1] = token; lsc[i1][p1] = s1;
      }
    }
    __syncthreads();
    if (t < NE) gbase[t] = atomicAdd(&counts[t], lcnt[t]);  // 8 global atomics/block
    __syncthreads();
#pragma unroll
    for (int e = 0; e < NE; e++) {
      int n = lcnt[e], gb0 = gbase[e];
      for (int s = t; s < n; s += 256) {
        tok_list[e * NT + gb0 + s] = ltok[e][s];
        scale_list[e * NT + gb0 + s] = lsc[e][s];
      }
    }
  } else if (b < 6272) {
    // ---- inp -> bf16 streaming cast: 2048 blocks x 4096 floats ----
    const int idx = b - 4224;
    const float4* s4 = (const float4*)(inp + (size_t)idx * 4096);
    ushort4* d4 = (ushort4*)(inp_bf + (size_t)idx * 4096);
    const int t = threadIdx.x;
#pragma unroll
    for (int j = 0; j < 4; j++) {
      float4 v = s4[t + j * 256];
      ushort4 o = { f2bf(v.x), f2bf(v.y), f2bf(v.z), f2bf(v.w) };
      d4[t + j * 256] = o;
    }
  } else {
    // ---- y-zero part: 2048 blocks x 4096 floats ----
    const int idx = b - 6272;
    float4* dst = (float4*)(y + (size_t)idx * 4096);
    f32x4 z = {0.f, 0.f, 0.f, 0.f};
#pragma unroll
    for (int j = 0; j < 4; j++)
      ((f32x4*)dst)[j * 256 + threadIdx.x] = z;
  }
}

// GEMM skeleton (r5/r10 champion): 128x128 tile, 256 thr (4 waves, 2x2),
// counted-vmcnt 3-buffer pipeline (T3/T4) + chunk-XOR LDS swizzle (T2, both-sides).
// Each wave issues exactly 4 loads per stage -> vmcnt(4) completes the oldest stage.

#define STAGE_TILE(base)                                      \
  do {                                                        \
    async_copy16(aP0, (char*)(base) + wv * 1024);             \
    async_copy16(aP1, (char*)(base) + 4096 + wv * 1024);      \
    async_copy16(bP0, (char*)(base) + 8192 + wv * 1024);      \
    async_copy16(bP1, (char*)(base) + 12288 + wv * 1024);     \
    aP0 += 32; aP1 += 32; bP0 += 32; bP1 += 32;               \
  } while (0)

// ---------------- GEMM1: h[off_e+gi] = gelu(x[tok] @ w1[e] + b1[e]), bf16 dense ----------------
// hbuf stores are NON-TEMPORAL: hbuf (128MB) is write-once here, consumed only by
// gemm2 (cold either way, gemm2 FETCH~197MB). Normal stores were evicting the w1t
// panels 16 mTile-blocks re-hit in L3 -> FETCH 143MB vs ~80MB unique (1.8x overfetch).
__global__ __launch_bounds__(256) void gemm1_kernel(
    const ushort* __restrict__ xbf, const ushort* __restrict__ w1t,
    const float* __restrict__ b1, const int* __restrict__ tok_list,
    const int* __restrict__ counts, ushort* __restrict__ hbuf) {
  const int b = blockIdx.x;
  const int e = b & 7;
  const int idx = b >> 3;        // 0..2047
  const int mTile = idx & 63;    // fastest
  const int nTile = idx >> 6;    // 0..31
  int off = 0;
  for (int i = 0; i < e; i++) off += counts[i];
  const int cnt = counts[e];
  if (mTile * 128 >= cnt) return;

  __shared__ __attribute__((aligned(128))) char ldsB[49152];  // 3 x (A 8KB + B 8KB)

  const int t = threadIdx.x;
  const int lane = t & 63, wv = t >> 6;
  const int wm = wv & 1, wn = wv >> 1;

  const int sr = t >> 2;                             // staging row 0..63
  const int sc = (((t & 3) ^ ((sr >> 1) & 3)) * 8);  // swizzled source chunk (ushorts)
  int gi0 = mTile * 128 + sr;      if (gi0 >= cnt) gi0 = cnt - 1;
  int gi1 = mTile * 128 + 64 + sr; if (gi1 >= cnt) gi1 = cnt - 1;
  const int tok0 = tok_list[e * NT + gi0];
  const int tok1 = tok_list[e * NT + gi1];
  const ushort* aP0 = xbf + (size_t)tok0 * DM + sc;
  const ushort* aP1 = xbf + (size_t)tok1 * DM + sc;
  const ushort* bP0 = w1t + ((size_t)e * DH + nTile * 128 + sr) * DM + sc;
  const ushort* bP1 = bP0 + (size_t)64 * DM;

  f32x4 zero = {0.f, 0.f, 0.f, 0.f};
  f32x4 acc[4][4];
#pragma unroll
  for (int i = 0; i < 4; i++)
#pragma unroll
    for (int j = 0; j < 4; j++) acc[i][j] = zero;

  const int quad = lane >> 4, lc = lane & 15;
  const int rq = quad ^ ((lc >> 1) & 3);          // swizzled chunk for reads

  auto compute = [&](const char* buf) {
    const char* A_ = buf;
    const char* B_ = buf + 8192;
    bf16x8 af[4], bfr[4];
#pragma unroll
    for (int mi = 0; mi < 4; mi++) {
      int row = wm * 64 + mi * 16 + lc;
      af[mi] = *(const bf16x8*)(A_ + row * 64 + rq * 16);
    }
#pragma unroll
    for (int ni = 0; ni < 4; ni++) {
      int row = wn * 64 + ni * 16 + lc;
      bfr[ni] = *(const bf16x8*)(B_ + row * 64 + rq * 16);
    }
#pragma unroll
    for (int mi = 0; mi < 4; mi++)
#pragma unroll
      for (int ni = 0; ni < 4; ni++)
        acc[mi][ni] = __builtin_amdgcn_mfma_f32_16x16x32_bf16(af[mi], bfr[ni], acc[mi][ni], 0, 0, 0);
  };

  const int NIT = DM / 32;  // 32
  STAGE_TILE(ldsB);
  STAGE_TILE(ldsB + 16384);
  int cur = 0;
  for (int tt = 0; tt < NIT - 1; ++tt) {
    asm volatile("s_waitcnt vmcnt(4)" ::: "memory");
    __builtin_amdgcn_s_barrier();
    if (tt + 2 < NIT) {
      int nx = cur + 2; if (nx >= 3) nx -= 3;
      STAGE_TILE(ldsB + nx * 16384);
    }
    compute(ldsB + cur * 16384);
    cur = (cur == 2) ? 0 : cur + 1;
  }
  asm volatile("s_waitcnt vmcnt(0)" ::: "memory");
  __builtin_amdgcn_s_barrier();
  compute(ldsB + cur * 16384);

  float bias[4];
#pragma unroll
  for (int ni = 0; ni < 4; ni++)
    bias[ni] = b1[(size_t)e * DH + nTile * 128 + wn * 64 + ni * 16 + lc];

#pragma unroll
  for (int mi = 0; mi < 4; mi++) {
#pragma unroll
    for (int r = 0; r < 4; r++) {
      int lr = wm * 64 + mi * 16 + quad * 4 + r;
      int gi = mTile * 128 + lr;
      if (gi < cnt) {
        ushort* hrow = hbuf + (size_t)(off + gi) * DH + nTile * 128 + wn * 64 + lc;
#pragma unroll
        for (int ni = 0; ni < 4; ni++) {
          float v = acc[mi][ni][r] + bias[ni];
          __builtin_nontemporal_store(f2bf(gelu_fast(v)), &hrow[ni * 16]);
        }
      }
    }
  }
}

// ---------------- GEMM2 (fused combine): y[tok] += s * (h @ w2[e] + b2[e]) ----------------
__global__ __launch_bounds__(256) void gemm2_kernel(
    const ushort* __restrict__ hbuf, const ushort* __restrict__ w2t,
    const float* __restrict__ b2, const int* __restrict__ tok_list,
    const float* __restrict__ scale_list, const int* __restrict__ counts,
    float* __restrict__ y) {
  const int b = blockIdx.x;
  const int e = b & 7;               // XCD pin
  const int idx = b >> 3;            // 0..511
  const int nTile = idx & 7;         // fastest: hbuf A-panel reuse
  const int mTile = idx >> 3;        // 0..63
  int off = 0;
  for (int i = 0; i < e; i++) off += counts[i];
  const int cnt = counts[e];
  if (mTile * 128 >= cnt) return;

  __shared__ __attribute__((aligned(128))) char ldsB[49152];  // 3 x (A 8KB + B 8KB)

  const int t = threadIdx.x;
  const int lane = t & 63, wv = t >> 6;
  const int wm = wv & 1, wn = wv >> 1;

  const int sr = t >> 2;
  const int sc = (((t & 3) ^ ((sr >> 1) & 3)) * 8);  // swizzled source chunk (ushorts)
  int gi0 = mTile * 128 + sr;      if (gi0 >= cnt) gi0 = cnt - 1;
  int gi1 = mTile * 128 + 64 + sr; if (gi1 >= cnt) gi1 = cnt - 1;
  const ushort* aP0 = hbuf + (size_t)(off + gi0) * DH + sc;
  const ushort* aP1 = hbuf + (size_t)(off + gi1) * DH + sc;
  const ushort* bP0 = w2t + ((size_t)e * DM + nTile * 128 + sr) * DH + sc;
  const ushort* bP1 = bP0 + (size_t)64 * DH;

  f32x4 zero = {0.f, 0.f, 0.f, 0.f};
  f32x4 acc[4][4];
#pragma unroll
  for (int i = 0; i < 4; i++)
#pragma unroll
    for (int j = 0; j < 4; j++) acc[i][j] = zero;

  const int quad = lane >> 4, lc = lane & 15;
  const int rq = quad ^ ((lc >> 1) & 3);

  auto compute = [&](const char* buf) {
    const char* A_ = buf;
    const char* B_ = buf + 8192;
    bf16x8 af[4], bfr[4];
#pragma unroll
    for (int mi = 0; mi < 4; mi++) {
      int row = wm * 64 + mi * 16 + lc;
      af[mi] = *(const bf16x8*)(A_ + row * 64 + rq * 16);
    }
#pragma unroll
    for (int ni = 0; ni < 4; ni++) {
      int row = wn * 64 + ni * 16 + lc;
      bfr[ni] = *(const bf16x8*)(B_ + row * 64 + rq * 16);
    }
#pragma unroll
    for (int mi = 0; mi < 4; mi++)
#pragma unroll
      for (int ni = 0; ni < 4; ni++)
        acc[mi][ni] = __builtin_amdgcn_mfma_f32_16x16x32_bf16(af[mi], bfr[ni], acc[mi][ni], 0, 0, 0);
  };

  const int NIT = DH / 32;  // 128
  STAGE_TILE(ldsB);
  STAGE_TILE(ldsB + 16384);
  int cur = 0;
  for (int tt = 0; tt < NIT - 1; ++tt) {
    asm volatile("s_waitcnt vmcnt(4)" ::: "memory");
    __builtin_amdgcn_s_barrier();
    if (tt + 2 < NIT) {
      int nx = cur + 2; if (nx >= 3) nx -= 3;
      STAGE_TILE(ldsB + nx * 16384);
    }
    compute(ldsB + cur * 16384);
    cur = (cur == 2) ? 0 : cur + 1;
  }
  asm volatile("s_waitcnt vmcnt(0)" ::: "memory");
  __builtin_amdgcn_s_barrier();
  compute(ldsB + cur * 16384);

  float bias[4];
#pragma unroll
  for (int ni = 0; ni < 4; ni++)
    bias[ni] = b2[(size_t)e * DM + nTile * 128 + wn * 64 + ni * 16 + lc];

#pragma unroll
  for (int mi = 0; mi < 4; mi++) {
#pragma unroll
    for (int r = 0; r < 4; r++) {
      int lr = wm * 64 + mi * 16 + quad * 4 + r;
      int gi = mTile * 128 + lr;
      if (gi < cnt) {
        int tok = tok_list[e * NT + gi];
        float s = scale_list[e * NT + gi];
        float* yrow = y + (size_t)tok * DM + nTile * 128 + wn * 64 + lc;
#pragma unroll
        for (int ni = 0; ni < 4; ni++) {
          float v = (acc[mi][ni][r] + bias[ni]) * s;
          unsafeAtomicAdd(&yrow[ni * 16], v);
        }
      }
    }
  }
}

extern "C" void kernel_launch(void* const* d_in, const int* in_sizes, int n_in,
                              void* d_out, int out_size, void* d_ws, size_t ws_size,
                              hipStream_t stream) {
  const float* inp = (const float*)d_in[0];
  const float* gw  = (const float*)d_in[1];
  const float* gb  = (const float*)d_in[2];
  const float* w1  = (const float*)d_in[3];
  const float* b1  = (const float*)d_in[4];
  const float* w2  = (const float*)d_in[5];
  const float* b2  = (const float*)d_in[6];
  float* y = (float*)d_out;

  // workspace layout (~286 MB total)
  char* ws = (char*)d_ws;
  ushort* inp_bf = (ushort*)ws;              ws += (size_t)NT * DM * 2;
  ushort* w1t    = (ushort*)ws;              ws += (size_t)NE * DH * DM * 2;
  ushort* w2t    = (ushort*)ws;              ws += (size_t)NE * DM * DH * 2;
  ushort* hbuf   = (ushort*)ws;              ws += (size_t)NP * DH * 2;
  int*    tok_list   = (int*)ws;             ws += (size_t)NE * NT * 4;
  float*  scale_list = (float*)ws;           ws += (size_t)NE * NT * 4;
  int*    counts     = (int*)ws;             ws += 256;

  hipMemsetAsync(counts, 0, 256, stream);

  // node 2: transpose (4096) + gate (128, block-aggregated) + cvt (2048) + y-zero (2048)
  fused_pre_kernel<<<8320, 256, 0, stream>>>(w1, w2, w1t, w2t, inp, gw, gb,
                                             inp_bf, counts, tok_list, scale_list, y);
  // node 3: GEMM1 (r5-verified: 128^2, 3-buffer counted-vmcnt, swizzled; nt hbuf stores)
  gemm1_kernel<<<NE * 32 * 64, 256, 0, stream>>>(inp_bf, w1t, b1, tok_list, counts, hbuf);
  // node 4: GEMM2 with fused scale+combine via atomics into y
  gemm2_kernel<<<NE * 8 * 64, 256, 0, stream>>>(hbuf, w2t, b2, tok_list, scale_list, counts, y);
}

// Round 13
// 752.769 us; speedup vs baseline: 1.0463x; 1.0463x over previous
//
#include <hip/hip_runtime.h>
#include <hip/hip_bf16.h>

#define NT 8192      // tokens
#define DM 1024      // d_model
#define NE 8         // experts
#define DH 4096      // d_hidden
#define NP (NT * 2)  // token-expert pairs (TOP_K = 2)

typedef __attribute__((ext_vector_type(8))) __bf16 bf16x8;
typedef __attribute__((ext_vector_type(4))) float f32x4;

__device__ __forceinline__ ushort f2bf(float f) {
  unsigned int x = __float_as_uint(f);
  unsigned int r = (x + 0x7fffu + ((x >> 16) & 1u)) >> 16;  // RNE
  return (ushort)r;
}

// exact tanh-gelu, rearranged: 0.5x(1+tanh(z)) = x*e^{2z}/(e^{2z}+1)
__device__ __forceinline__ float gelu_fast(float x) {
  float x2 = x * x;
  float t = __builtin_fmaf(x2, 0.044715f, 1.0f);
  float m = x * t * 2.3025851f;
  m = fminf(m, 126.0f);
  float p = __builtin_amdgcn_exp2f(m);
  return x * p * __builtin_amdgcn_rcpf(p + 1.0f);
}

__device__ __forceinline__ void async_copy16(const void* gsrc, void* ldst) {
  __builtin_amdgcn_global_load_lds(
      (const __attribute__((address_space(1))) void*)gsrc,
      (__attribute__((address_space(3))) void*)ldst, 16, 0, 0);
}

// ---------------- fused pre-pass: ONE kernel, four independent block ranges ----------------
//   b < 128  : gating, BLOCK-AGGREGATED (128 blocks x 64 tokens) — FIRST: longest-latency
//              blocks start earliest instead of forming the grid tail
//   b < 4224 : weight transpose+cvt (w1 -> w1t, w2 -> w2t), 128x128 tiles
//   b < 6272 : inp -> bf16 streaming cast (2048 blocks)
//   b < 8320 : zero y (gemm2 accumulates into y with atomics)
// (r10-verified structure; r12's NT-store regression reverted.)
__global__ __launch_bounds__(256) void fused_pre_kernel(
    const float* __restrict__ w1, const float* __restrict__ w2,
    ushort* __restrict__ w1t, ushort* __restrict__ w2t,
    const float* __restrict__ inp, const float* __restrict__ gw,
    const float* __restrict__ gb, ushort* __restrict__ inp_bf,
    int* __restrict__ counts, int* __restrict__ tok_list,
    float* __restrict__ scale_list, float* __restrict__ y) {
  __shared__ ushort tileT[128][136];   // transpose branch
  __shared__ int   lcnt[NE];           // gate branch
  __shared__ int   gbase[NE];
  __shared__ int   ltok[NE][64];       // per-token top2 experts distinct -> <=64/expert
  __shared__ float lsc[NE][64];
  const int b = blockIdx.x;

  if (b < 128) {
    // ---- gating part: 64 tokens/block, block-aggregated appends (r10-verified) ----
    const int t = threadIdx.x;
    if (t < NE) lcnt[t] = 0;
    __syncthreads();
    const int wave = t >> 6, lane = t & 63;
    const int tokBase = b * 64 + wave * 16;
    for (int ti = 0; ti < 16; ti++) {
      const int token = tokBase + ti;
      const float* x = inp + (size_t)token * DM;
      float acc[NE];
#pragma unroll
      for (int e = 0; e < NE; e++) acc[e] = 0.f;
#pragma unroll
      for (int j = 0; j < 16; j++) {
        int idx = j * 64 + lane;
        float xv = x[idx];
        const float4* g = (const float4*)(gw + (size_t)idx * NE);
        float4 g0 = g[0], g1 = g[1];
        acc[0] += xv * g0.x; acc[1] += xv * g0.y; acc[2] += xv * g0.z; acc[3] += xv * g0.w;
        acc[4] += xv * g1.x; acc[5] += xv * g1.y; acc[6] += xv * g1.z; acc[7] += xv * g1.w;
      }
#pragma unroll
      for (int e = 0; e < NE; e++) {
        for (int off = 32; off; off >>= 1) acc[e] += __shfl_xor(acc[e], off, 64);
      }
      if (lane == 0) {
        float v[NE];
#pragma unroll
        for (int e = 0; e < NE; e++) v[e] = acc[e] + gb[e];
        int i0 = 0; float b0 = v[0];
#pragma unroll
        for (int e = 1; e < NE; e++) if (v[e] > b0) { b0 = v[e]; i0 = e; }
        int i1 = -1; float b1v = -INFINITY;
#pragma unroll
        for (int e = 0; e < NE; e++) if (e != i0 && v[e] > b1v) { b1v = v[e]; i1 = e; }
        float s1 = 1.f / (1.f + __expf(b0 - b1v));  // softmax over the two selected logits
        float s0 = 1.f - s1;
        int p0 = atomicAdd(&lcnt[i0], 1);           // LDS atomic (fast)
        ltok[i0][p0] = token; lsc[i0][p0] = s0;
        int p1 = atomicAdd(&lcnt[i1], 1);
        ltok[i1][p1] = token; lsc[i1][p1] = s1;
      }
    }
    __syncthreads();
    if (t < NE) gbase[t] = atomicAdd(&counts[t], lcnt[t]);  // 8 global atomics/block
    __syncthreads();
#pragma unroll
    for (int e = 0; e < NE; e++) {
      int n = lcnt[e], gb0 = gbase[e];
      for (int s = t; s < n; s += 256) {
        tok_list[e * NT + gb0 + s] = ltok[e][s];
        scale_list[e * NT + gb0 + s] = lsc[e][s];
      }
    }
  } else if (b < 4224) {
    // ---- transpose part: 128x128 tile, register 4x4 micro-transpose ----
    const int tb = b - 128;
    const int which = tb >> 11;        // 0 = w1, 1 = w2
    const int rem = tb & 2047;
    const int e = rem >> 8;            // expert
    const int bb = rem & 255;          // 256 tiles per expert-weight
    const float* src;
    ushort* dst;
    int R, C, r0, c0;
    if (which == 0) {
      src = w1 + (size_t)e * DM * DH; dst = w1t + (size_t)e * DM * DH;
      R = DM; C = DH;
      r0 = (bb & 7) * 128;   c0 = (bb >> 3) * 128;
    } else {
      src = w2 + (size_t)e * DM * DH; dst = w2t + (size_t)e * DM * DH;
      R = DH; C = DM;
      r0 = (bb & 31) * 128;  c0 = (bb >> 5) * 128;
    }
    const int tx = threadIdx.x & 31;
    const int ty = threadIdx.x >> 5;
#pragma unroll
    for (int i = 0; i < 4; i++) {
      int rb = ty + 8 * i;
      const float* sp = src + (size_t)(r0 + 4 * rb) * C + c0 + 4 * tx;
      float4 a0 = *(const float4*)(sp);
      float4 a1 = *(const float4*)(sp + C);
      float4 a2 = *(const float4*)(sp + 2 * (size_t)C);
      float4 a3 = *(const float4*)(sp + 3 * (size_t)C);
      ushort4 o0 = { f2bf(a0.x), f2bf(a1.x), f2bf(a2.x), f2bf(a3.x) };
      ushort4 o1 = { f2bf(a0.y), f2bf(a1.y), f2bf(a2.y), f2bf(a3.y) };
      ushort4 o2 = { f2bf(a0.z), f2bf(a1.z), f2bf(a2.z), f2bf(a3.z) };
      ushort4 o3 = { f2bf(a0.w), f2bf(a1.w), f2bf(a2.w), f2bf(a3.w) };
      *(ushort4*)(&tileT[4 * tx + 0][4 * rb]) = o0;
      *(ushort4*)(&tileT[4 * tx + 1][4 * rb]) = o1;
      *(ushort4*)(&tileT[4 * tx + 2][4 * rb]) = o2;
      *(ushort4*)(&tileT[4 * tx + 3][4 * rb]) = o3;
    }
    __syncthreads();
    const int kx = threadIdx.x & 31;
    const int ny = threadIdx.x >> 5;
#pragma unroll
    for (int i = 0; i < 16; i++) {
      int n = ny + 8 * i;
      *(ushort4*)(dst + (size_t)(c0 + n) * R + r0 + 4 * kx) =
          *(const ushort4*)(&tileT[n][4 * kx]);
    }
  } else if (b < 6272) {
    // ---- inp -> bf16 streaming cast: 2048 blocks x 4096 floats ----
    const int idx = b - 4224;
    const float4* s4 = (const float4*)(inp + (size_t)idx * 4096);
    ushort4* d4 = (ushort4*)(inp_bf + (size_t)idx * 4096);
    const int t = threadIdx.x;
#pragma unroll
    for (int j = 0; j < 4; j++) {
      float4 v = s4[t + j * 256];
      ushort4 o = { f2bf(v.x), f2bf(v.y), f2bf(v.z), f2bf(v.w) };
      d4[t + j * 256] = o;
    }
  } else {
    // ---- y-zero part: 2048 blocks x 4096 floats ----
    const int idx = b - 6272;
    float4* dst = (float4*)(y + (size_t)idx * 4096);
    f32x4 z = {0.f, 0.f, 0.f, 0.f};
#pragma unroll
    for (int j = 0; j < 4; j++)
      ((f32x4*)dst)[j * 256 + threadIdx.x] = z;
  }
}

// GEMM skeleton (r5/r10 champion): 128x128 tile, 256 thr (4 waves, 2x2),
// counted-vmcnt 3-buffer pipeline (T3/T4) + chunk-XOR LDS swizzle (T2, both-sides).
// Each wave issues exactly 4 loads per stage -> vmcnt(4) completes the oldest stage.

#define STAGE_TILE(base)                                      \
  do {                                                        \
    async_copy16(aP0, (char*)(base) + wv * 1024);             \
    async_copy16(aP1, (char*)(base) + 4096 + wv * 1024);      \
    async_copy16(bP0, (char*)(base) + 8192 + wv * 1024);      \
    async_copy16(bP1, (char*)(base) + 12288 + wv * 1024);     \
    aP0 += 32; aP1 += 32; bP0 += 32; bP1 += 32;               \
  } while (0)

// ---------------- GEMM1: h[off_e+gi] = gelu(x[tok] @ w1[e] + b1[e]), bf16 dense ----------------
__global__ __launch_bounds__(256) void gemm1_kernel(
    const ushort* __restrict__ xbf, const ushort* __restrict__ w1t,
    const float* __restrict__ b1, const int* __restrict__ tok_list,
    const int* __restrict__ counts, ushort* __restrict__ hbuf) {
  const int b = blockIdx.x;
  const int e = b & 7;
  const int idx = b >> 3;        // 0..2047
  const int mTile = idx & 63;    // fastest
  const int nTile = idx >> 6;    // 0..31
  int off = 0;
  for (int i = 0; i < e; i++) off += counts[i];
  const int cnt = counts[e];
  if (mTile * 128 >= cnt) return;

  __shared__ __attribute__((aligned(128))) char ldsB[49152];  // 3 x (A 8KB + B 8KB)

  const int t = threadIdx.x;
  const int lane = t & 63, wv = t >> 6;
  const int wm = wv & 1, wn = wv >> 1;

  const int sr = t >> 2;                             // staging row 0..63
  const int sc = (((t & 3) ^ ((sr >> 1) & 3)) * 8);  // swizzled source chunk (ushorts)
  int gi0 = mTile * 128 + sr;      if (gi0 >= cnt) gi0 = cnt - 1;
  int gi1 = mTile * 128 + 64 + sr; if (gi1 >= cnt) gi1 = cnt - 1;
  const int tok0 = tok_list[e * NT + gi0];
  const int tok1 = tok_list[e * NT + gi1];
  const ushort* aP0 = xbf + (size_t)tok0 * DM + sc;
  const ushort* aP1 = xbf + (size_t)tok1 * DM + sc;
  const ushort* bP0 = w1t + ((size_t)e * DH + nTile * 128 + sr) * DM + sc;
  const ushort* bP1 = bP0 + (size_t)64 * DM;

  f32x4 zero = {0.f, 0.f, 0.f, 0.f};
  f32x4 acc[4][4];
#pragma unroll
  for (int i = 0; i < 4; i++)
#pragma unroll
    for (int j = 0; j < 4; j++) acc[i][j] = zero;

  const int quad = lane >> 4, lc = lane & 15;
  const int rq = quad ^ ((lc >> 1) & 3);          // swizzled chunk for reads

  auto compute = [&](const char* buf) {
    const char* A_ = buf;
    const char* B_ = buf + 8192;
    bf16x8 af[4], bfr[4];
#pragma unroll
    for (int mi = 0; mi < 4; mi++) {
      int row = wm * 64 + mi * 16 + lc;
      af[mi] = *(const bf16x8*)(A_ + row * 64 + rq * 16);
    }
#pragma unroll
    for (int ni = 0; ni < 4; ni++) {
      int row = wn * 64 + ni * 16 + lc;
      bfr[ni] = *(const bf16x8*)(B_ + row * 64 + rq * 16);
    }
#pragma unroll
    for (int mi = 0; mi < 4; mi++)
#pragma unroll
      for (int ni = 0; ni < 4; ni++)
        acc[mi][ni] = __builtin_amdgcn_mfma_f32_16x16x32_bf16(af[mi], bfr[ni], acc[mi][ni], 0, 0, 0);
  };

  const int NIT = DM / 32;  // 32
  STAGE_TILE(ldsB);
  STAGE_TILE(ldsB + 16384);
  int cur = 0;
  for (int tt = 0; tt < NIT - 1; ++tt) {
    asm volatile("s_waitcnt vmcnt(4)" ::: "memory");
    __builtin_amdgcn_s_barrier();
    if (tt + 2 < NIT) {
      int nx = cur + 2; if (nx >= 3) nx -= 3;
      STAGE_TILE(ldsB + nx * 16384);
    }
    compute(ldsB + cur * 16384);
    cur = (cur == 2) ? 0 : cur + 1;
  }
  asm volatile("s_waitcnt vmcnt(0)" ::: "memory");
  __builtin_amdgcn_s_barrier();
  compute(ldsB + cur * 16384);

  float bias[4];
#pragma unroll
  for (int ni = 0; ni < 4; ni++)
    bias[ni] = b1[(size_t)e * DH + nTile * 128 + wn * 64 + ni * 16 + lc];

#pragma unroll
  for (int mi = 0; mi < 4; mi++) {
#pragma unroll
    for (int r = 0; r < 4; r++) {
      int lr = wm * 64 + mi * 16 + quad * 4 + r;
      int gi = mTile * 128 + lr;
      if (gi < cnt) {
        ushort* hrow = hbuf + (size_t)(off + gi) * DH + nTile * 128 + wn * 64 + lc;
#pragma unroll
        for (int ni = 0; ni < 4; ni++) {
          float v = acc[mi][ni][r] + bias[ni];
          hrow[ni * 16] = f2bf(gelu_fast(v));
        }
      }
    }
  }
}

// ---------------- GEMM2 (fused combine): y[tok] += s * (h @ w2[e] + b2[e]) ----------------
__global__ __launch_bounds__(256) void gemm2_kernel(
    const ushort* __restrict__ hbuf, const ushort* __restrict__ w2t,
    const float* __restrict__ b2, const int* __restrict__ tok_list,
    const float* __restrict__ scale_list, const int* __restrict__ counts,
    float* __restrict__ y) {
  const int b = blockIdx.x;
  const int e = b & 7;               // XCD pin
  const int idx = b >> 3;            // 0..511
  const int nTile = idx & 7;         // fastest: hbuf A-panel reuse
  const int mTile = idx >> 3;        // 0..63
  int off = 0;
  for (int i = 0; i < e; i++) off += counts[i];
  const int cnt = counts[e];
  if (mTile * 128 >= cnt) return;

  __shared__ __attribute__((aligned(128))) char ldsB[49152];  // 3 x (A 8KB + B 8KB)

  const int t = threadIdx.x;
  const int lane = t & 63, wv = t >> 6;
  const int wm = wv & 1, wn = wv >> 1;

  const int sr = t >> 2;
  const int sc = (((t & 3) ^ ((sr >> 1) & 3)) * 8);  // swizzled source chunk (ushorts)
  int gi0 = mTile * 128 + sr;      if (gi0 >= cnt) gi0 = cnt - 1;
  int gi1 = mTile * 128 + 64 + sr; if (gi1 >= cnt) gi1 = cnt - 1;
  const ushort* aP0 = hbuf + (size_t)(off + gi0) * DH + sc;
  const ushort* aP1 = hbuf + (size_t)(off + gi1) * DH + sc;
  const ushort* bP0 = w2t + ((size_t)e * DM + nTile * 128 + sr) * DH + sc;
  const ushort* bP1 = bP0 + (size_t)64 * DH;

  f32x4 zero = {0.f, 0.f, 0.f, 0.f};
  f32x4 acc[4][4];
#pragma unroll
  for (int i = 0; i < 4; i++)
#pragma unroll
    for (int j = 0; j < 4; j++) acc[i][j] = zero;

  const int quad = lane >> 4, lc = lane & 15;
  const int rq = quad ^ ((lc >> 1) & 3);

  auto compute = [&](const char* buf) {
    const char* A_ = buf;
    const char* B_ = buf + 8192;
    bf16x8 af[4], bfr[4];
#pragma unroll
    for (int mi = 0; mi < 4; mi++) {
      int row = wm * 64 + mi * 16 + lc;
      af[mi] = *(const bf16x8*)(A_ + row * 64 + rq * 16);
    }
#pragma unroll
    for (int ni = 0; ni < 4; ni++) {
      int row = wn * 64 + ni * 16 + lc;
      bfr[ni] = *(const bf16x8*)(B_ + row * 64 + rq * 16);
    }
#pragma unroll
    for (int mi = 0; mi < 4; mi++)
#pragma unroll
      for (int ni = 0; ni < 4; ni++)
        acc[mi][ni] = __builtin_amdgcn_mfma_f32_16x16x32_bf16(af[mi], bfr[ni], acc[mi][ni], 0, 0, 0);
  };

  const int NIT = DH / 32;  // 128
  STAGE_TILE(ldsB);
  STAGE_TILE(ldsB + 16384);
  int cur = 0;
  for (int tt = 0; tt < NIT - 1; ++tt) {
    asm volatile("s_waitcnt vmcnt(4)" ::: "memory");
    __builtin_amdgcn_s_barrier();
    if (tt + 2 < NIT) {
      int nx = cur + 2; if (nx >= 3) nx -= 3;
      STAGE_TILE(ldsB + nx * 16384);
    }
    compute(ldsB + cur * 16384);
    cur = (cur == 2) ? 0 : cur + 1;
  }
  asm volatile("s_waitcnt vmcnt(0)" ::: "memory");
  __builtin_amdgcn_s_barrier();
  compute(ldsB + cur * 16384);

  float bias[4];
#pragma unroll
  for (int ni = 0; ni < 4; ni++)
    bias[ni] = b2[(size_t)e * DM + nTile * 128 + wn * 64 + ni * 16 + lc];

#pragma unroll
  for (int mi = 0; mi < 4; mi++) {
#pragma unroll
    for (int r = 0; r < 4; r++) {
      int lr = wm * 64 + mi * 16 + quad * 4 + r;
      int gi = mTile * 128 + lr;
      if (gi < cnt) {
        int tok = tok_list[e * NT + gi];
        float s = scale_list[e * NT + gi];
        float* yrow = y + (size_t)tok * DM + nTile * 128 + wn * 64 + lc;
#pragma unroll
        for (int ni = 0; ni < 4; ni++) {
          float v = (acc[mi][ni][r] + bias[ni]) * s;
          unsafeAtomicAdd(&yrow[ni * 16], v);
        }
      }
    }
  }
}

extern "C" void kernel_launch(void* const* d_in, const int* in_sizes, int n_in,
                              void* d_out, int out_size, void* d_ws, size_t ws_size,
                              hipStream_t stream) {
  const float* inp = (const float*)d_in[0];
  const float* gw  = (const float*)d_in[1];
  const float* gb  = (const float*)d_in[2];
  const float* w1  = (const float*)d_in[3];
  const float* b1  = (const float*)d_in[4];
  const float* w2  = (const float*)d_in[5];
  const float* b2  = (const float*)d_in[6];
  float* y = (float*)d_out;

  // workspace layout (~286 MB total)
  char* ws = (char*)d_ws;
  ushort* inp_bf = (ushort*)ws;              ws += (size_t)NT * DM * 2;
  ushort* w1t    = (ushort*)ws;              ws += (size_t)NE * DH * DM * 2;
  ushort* w2t    = (ushort*)ws;              ws += (size_t)NE * DM * DH * 2;
  ushort* hbuf   = (ushort*)ws;              ws += (size_t)NP * DH * 2;
  int*    tok_list   = (int*)ws;             ws += (size_t)NE * NT * 4;
  float*  scale_list = (float*)ws;           ws += (size_t)NE * NT * 4;
  int*    counts     = (int*)ws;             ws += 256;

  hipMemsetAsync(counts, 0, 256, stream);

  // node 2: gate (128, first — longest blocks start earliest) + transpose (4096)
  //         + cvt (2048) + y-zero (2048)
  fused_pre_kernel<<<8320, 256, 0, stream>>>(w1, w2, w1t, w2t, inp, gw, gb,
                                             inp_bf, counts, tok_list, scale_list, y);
  // node 3: GEMM1 (r5-verified: 128^2, 3-buffer counted-vmcnt, swizzled)
  gemm1_kernel<<<NE * 32 * 64, 256, 0, stream>>>(inp_bf, w1t, b1, tok_list, counts, hbuf);
  // node 4: GEMM2 with fused scale+combine via atomics into y
  gemm2_kernel<<<NE * 8 * 64, 256, 0, stream>>>(hbuf, w2t, b2, tok_list, scale_list, counts, y);
}